// Round 1
// baseline (42735.880 us; speedup 1.0000x reference)
//
#include <hip/hip_runtime.h>
#include <hip/hip_bf16.h>

#define BATCH 16
#define CH    256
#define HH    96
#define WW    96
#define HWSZ  9216     // 96*96
#define FCH   256
#define PP    256      // 16*16 pooled positions

// ---------------------------------------------------------------------------
// Kernel 1a: 6x6 average pool -> pooled[b,c,p] (p = pr*16+pc)
// grid: B*C blocks, 256 threads
__global__ void pool16_k(const float* __restrict__ feat, float* __restrict__ pooled)
{
    int bc = blockIdx.x;
    const float* src = feat + (size_t)bc * HWSZ;
    int t = threadIdx.x;
    int pr = t >> 4, pc = t & 15;
    float s = 0.f;
#pragma unroll
    for (int i = 0; i < 6; ++i)
#pragma unroll
        for (int j = 0; j < 6; ++j)
            s += src[(pr * 6 + i) * WW + pc * 6 + j];
    pooled[(size_t)bc * PP + t] = s * (1.0f / 36.0f);
}

// ---------------------------------------------------------------------------
// Kernel 1b: rnorm[b,hw] = 1 / max(sqrt(sum_c feat^2), 1e-12)
// grid: (HWSZ/256, B), 256 threads
__global__ void l2norm_k(const float* __restrict__ feat, float* __restrict__ rnorm)
{
    int b = blockIdx.y;
    int hw = blockIdx.x * 256 + threadIdx.x;
    const float* src = feat + (size_t)b * CH * HWSZ + hw;
    float s = 0.f;
#pragma unroll 4
    for (int c = 0; c < CH; ++c) {
        float v = src[(size_t)c * HWSZ];
        s += v * v;
    }
    float n = sqrtf(s);
    rnorm[b * HWSZ + hw] = 1.0f / fmaxf(n, 1e-12f);
}

// ---------------------------------------------------------------------------
// Kernel 2: M[b,o,c] = sum_p W1[o,p] * pooled[b,c,p]
// grid: (16 cTiles, 16 oTiles, B), block (16,16)
__global__ void gemmM_k(const float* __restrict__ W1, const float* __restrict__ pooled,
                        float* __restrict__ Mmat)
{
    int b = blockIdx.z;
    int o0 = blockIdx.y * 16, c0 = blockIdx.x * 16;
    int ty = threadIdx.y, tx = threadIdx.x;
    __shared__ float Ws[16][17], Ps[16][17];
    float acc = 0.f;
    for (int p0 = 0; p0 < PP; p0 += 16) {
        Ws[ty][tx] = W1[(o0 + ty) * PP + p0 + tx];
        Ps[ty][tx] = pooled[((size_t)b * CH + (c0 + ty)) * PP + p0 + tx];
        __syncthreads();
#pragma unroll
        for (int p = 0; p < 16; ++p) acc += Ws[ty][p] * Ps[tx][p];
        __syncthreads();
    }
    Mmat[((size_t)b * FCH + o0 + ty) * CH + c0 + tx] = acc;
}

// ---------------------------------------------------------------------------
// Kernel 3: y1[b,o,hw] = (sum_c M[b,o,c] * feat[b,c,hw]) * rnorm[b,hw]
// per-batch GEMM 256x9216x256. BM=64,BN=64,BK=16, 256 threads, 4x4/thread.
// grid: (144, 4, nb)
__global__ void gemmY_k(const float* __restrict__ Mmat, const float* __restrict__ feat,
                        const float* __restrict__ rnorm, float* __restrict__ y1, int b0)
{
    int bl = blockIdx.z;          // local batch
    int bg = b0 + bl;             // global batch
    int brow = blockIdx.y * 64;   // o
    int bcol = blockIdx.x * 64;   // hw
    const float* A  = Mmat + (size_t)bg * FCH * CH;
    const float* Bm = feat + (size_t)bg * CH * HWSZ;
    __shared__ float As[64][17];
    __shared__ float Bs[16][64];
    int tid = threadIdx.x;
    int tr = tid >> 4, tc = tid & 15;
    float acc[4][4] = {};
    for (int k0 = 0; k0 < CH; k0 += 16) {
        {
            int e = tid * 4;
            int r = e >> 4, col = e & 15;
            float4 v = *(const float4*)&A[(size_t)(brow + r) * CH + k0 + col];
            As[r][col] = v.x; As[r][col + 1] = v.y; As[r][col + 2] = v.z; As[r][col + 3] = v.w;
        }
        {
            int e = tid * 4;
            int r = e >> 6, col = e & 63;
            float4 v = *(const float4*)&Bm[(size_t)(k0 + r) * HWSZ + bcol + col];
            *(float4*)&Bs[r][col] = v;
        }
        __syncthreads();
#pragma unroll
        for (int k = 0; k < 16; ++k) {
            float a[4], bb[4];
#pragma unroll
            for (int i = 0; i < 4; ++i) a[i] = As[tr * 4 + i][k];
#pragma unroll
            for (int j = 0; j < 4; ++j) bb[j] = Bs[k][tc * 4 + j];
#pragma unroll
            for (int i = 0; i < 4; ++i)
#pragma unroll
                for (int j = 0; j < 4; ++j) acc[i][j] += a[i] * bb[j];
        }
        __syncthreads();
    }
    float4 rn = *(const float4*)&rnorm[(size_t)bg * HWSZ + bcol + tc * 4];
#pragma unroll
    for (int i = 0; i < 4; ++i) {
        float4 v;
        v.x = acc[i][0] * rn.x; v.y = acc[i][1] * rn.y;
        v.z = acc[i][2] * rn.z; v.w = acc[i][3] * rn.w;
        *(float4*)&y1[((size_t)bl * FCH + brow + tr * 4 + i) * HWSZ + bcol + tc * 4] = v;
    }
}

// ---------------------------------------------------------------------------
// Kernel 4: instance-norm stats per (b,o): mu, istd
// grid: nb*256 blocks, 256 threads
__global__ void instats_k(const float* __restrict__ y1, float* __restrict__ mu,
                          float* __restrict__ istd)
{
    int bo = blockIdx.x;
    const float* src = y1 + (size_t)bo * HWSZ;
    float s = 0.f, s2 = 0.f;
    for (int i = threadIdx.x; i < HWSZ; i += 256) {
        float v = src[i];
        s += v; s2 += v * v;
    }
#pragma unroll
    for (int off = 32; off > 0; off >>= 1) {
        s  += __shfl_down(s,  off, 64);
        s2 += __shfl_down(s2, off, 64);
    }
    __shared__ float sh[8];
    int wid = threadIdx.x >> 6, lane = threadIdx.x & 63;
    if (lane == 0) { sh[wid] = s; sh[4 + wid] = s2; }
    __syncthreads();
    if (threadIdx.x == 0) {
        float S  = sh[0] + sh[1] + sh[2] + sh[3];
        float S2 = sh[4] + sh[5] + sh[6] + sh[7];
        float m   = S  * (1.0f / HWSZ);
        float var = S2 * (1.0f / HWSZ) - m * m;
        if (var < 0.f) var = 0.f;
        mu[bo]   = m;
        istd[bo] = rsqrtf(var + 1e-5f);
    }
}

// ---------------------------------------------------------------------------
// Kernel 5: in-place a = relu((y1 - mu) * istd)
// grid: nb*256*36 blocks, 256 threads
__global__ void normrelu_k(float* __restrict__ y1, const float* __restrict__ mu,
                           const float* __restrict__ istd)
{
    size_t i = (size_t)blockIdx.x * 256 + threadIdx.x;
    int bo = (int)(i / HWSZ);
    float v = (y1[i] - mu[bo]) * istd[bo];
    y1[i] = v > 0.f ? v : 0.f;
}

// ---------------------------------------------------------------------------
// Kernel 6: 3x3 SAME conv: out[b,o,h,w] = b2[o] + sum_{c,kh,kw} W2[o,c,kh,kw]*a[b,c,h+kh-1,w+kw-1]
// grid: (36 tiles, 256 o, nb), 256 threads (16x16 spatial tile)
__global__ void conv3_k(const float* __restrict__ a, const float* __restrict__ W2,
                        const float* __restrict__ b2, float* __restrict__ out)
{
    int tile = blockIdx.x;
    int o = blockIdx.y, bl = blockIdx.z;
    int th = (tile / 6) * 16, tw = (tile % 6) * 16;
    int ty = threadIdx.x >> 4, tx = threadIdx.x & 15;
    __shared__ float t[18][18];
    __shared__ float wsh[9];
    float acc = 0.f;
    const float* ab = a + (size_t)bl * CH * HWSZ;
    for (int c = 0; c < CH; ++c) {
        for (int e = threadIdx.x; e < 324; e += 256) {
            int r = e / 18, col = e % 18;
            int gh = th + r - 1, gw = tw + col - 1;
            float v = 0.f;
            if (gh >= 0 && gh < HH && gw >= 0 && gw < WW)
                v = ab[(size_t)c * HWSZ + gh * WW + gw];
            t[r][col] = v;
        }
        if (threadIdx.x < 9) wsh[threadIdx.x] = W2[(size_t)(o * CH + c) * 9 + threadIdx.x];
        __syncthreads();
#pragma unroll
        for (int kh = 0; kh < 3; ++kh)
#pragma unroll
            for (int kw = 0; kw < 3; ++kw)
                acc += wsh[kh * 3 + kw] * t[ty + kh][tx + kw];
        __syncthreads();
    }
    out[((size_t)bl * FCH + o) * HWSZ + (th + ty) * WW + tw + tx] = acc + b2[o];
}

// ---------------------------------------------------------------------------
extern "C" void kernel_launch(void* const* d_in, const int* in_sizes, int n_in,
                              void* d_out, int out_size, void* d_ws, size_t ws_size,
                              hipStream_t stream)
{
    const float* Fir  = (const float*)d_in[0];
    const float* Fvis = (const float*)d_in[1];
    const float* W1   = (const float*)d_in[2];
    // d_in[3] = b1: mathematically canceled by InstanceNorm -> unused
    const float* W2   = (const float*)d_in[4];
    const float* b2   = (const float*)d_in[5];
    float* out = (float*)d_out;

    char* w = (char*)d_ws;
    const size_t poolB = (size_t)BATCH * CH * PP * 4;   // 4 MB
    const size_t MB_   = (size_t)BATCH * FCH * CH * 4;  // 4 MB
    const size_t rnB   = (size_t)BATCH * HWSZ * 4;      // 0.56 MB
    const size_t stB   = (size_t)BATCH * FCH * 4;       // 16 KB
    const size_t fixed = poolB + MB_ + rnB + 2 * stB;
    float* pooled = (float*)w;
    float* Mmat   = (float*)(w + poolB);
    float* rnorm  = (float*)(w + poolB + MB_);
    float* mu     = (float*)(w + poolB + MB_ + rnB);
    float* istd   = (float*)(w + poolB + MB_ + rnB + stB);
    float* y1     = (float*)(w + fixed);

    const size_t perBatch = (size_t)FCH * HWSZ * 4;     // 9.4 MB
    size_t avail = ws_size > fixed ? ws_size - fixed : 0;
    int NB = (int)(avail / perBatch);
    if (NB > BATCH) NB = BATCH;
    if (NB < 1) NB = 1;   // last resort; needs ~19 MB of ws

    for (int f = 0; f < 2; ++f) {
        const float* feat = (f == 0) ? Fir : Fvis;   // output order: IR first
        float* o_ = out + (size_t)f * BATCH * FCH * HWSZ;

        pool16_k<<<BATCH * CH, 256, 0, stream>>>(feat, pooled);
        l2norm_k<<<dim3(HWSZ / 256, BATCH), 256, 0, stream>>>(feat, rnorm);
        gemmM_k<<<dim3(16, 16, BATCH), dim3(16, 16), 0, stream>>>(W1, pooled, Mmat);

        for (int b0 = 0; b0 < BATCH; b0 += NB) {
            int nb = BATCH - b0 < NB ? BATCH - b0 : NB;
            gemmY_k<<<dim3(HWSZ / 64, FCH / 64, nb), 256, 0, stream>>>(Mmat, feat, rnorm, y1, b0);
            instats_k<<<nb * FCH, 256, 0, stream>>>(y1, mu + (size_t)b0 * FCH, istd + (size_t)b0 * FCH);
            normrelu_k<<<nb * FCH * (HWSZ / 256), 256, 0, stream>>>(y1, mu + (size_t)b0 * FCH, istd + (size_t)b0 * FCH);
            conv3_k<<<dim3(36, FCH, nb), 256, 0, stream>>>(y1, W2, b2, o_ + (size_t)b0 * FCH * HWSZ);
        }
    }
}

// Round 2
// 1570.075 us; speedup vs baseline: 27.2190x; 27.2190x over previous
//
#include <hip/hip_runtime.h>
#include <hip/hip_bf16.h>

#define BATCH 16
#define CH    256
#define HH    96
#define WW    96
#define HWSZ  9216     // 96*96
#define FCH   256
#define PP    256      // 16*16 pooled positions

typedef float f32x4 __attribute__((ext_vector_type(4)));
typedef short bf16x8 __attribute__((ext_vector_type(8)));

#define APAD_ELEMS 2458624   // 98*32*98*8 ushorts per batch
#define APAD_CHUNKS 307328   // /8

// ---------------------------------------------------------------------------
// Kernel 1a: 6x6 average pool -> pooled[b,c,p]
__global__ void pool16_k(const float* __restrict__ feat, float* __restrict__ pooled)
{
    int bc = blockIdx.x;
    const float* src = feat + (size_t)bc * HWSZ;
    int t = threadIdx.x;
    int pr = t >> 4, pc = t & 15;
    float s = 0.f;
#pragma unroll
    for (int i = 0; i < 6; ++i)
#pragma unroll
        for (int j = 0; j < 6; ++j)
            s += src[(pr * 6 + i) * WW + pc * 6 + j];
    pooled[(size_t)bc * PP + t] = s * (1.0f / 36.0f);
}

// ---------------------------------------------------------------------------
// Kernel 1b: rnorm[b,hw] = 1/max(||feat[:,hw]||, 1e-12)
__global__ void l2norm_k(const float* __restrict__ feat, float* __restrict__ rnorm)
{
    int b = blockIdx.y;
    int hw = blockIdx.x * 256 + threadIdx.x;
    const float* src = feat + (size_t)b * CH * HWSZ + hw;
    float s = 0.f;
#pragma unroll 4
    for (int c = 0; c < CH; ++c) {
        float v = src[(size_t)c * HWSZ];
        s += v * v;
    }
    float n = sqrtf(s);
    rnorm[b * HWSZ + hw] = 1.0f / fmaxf(n, 1e-12f);
}

// ---------------------------------------------------------------------------
// Kernel 2: M[b,o,c] = sum_p W1[o,p] * pooled[b,c,p]
__global__ void gemmM_k(const float* __restrict__ W1, const float* __restrict__ pooled,
                        float* __restrict__ Mmat)
{
    int b = blockIdx.z;
    int o0 = blockIdx.y * 16, c0 = blockIdx.x * 16;
    int ty = threadIdx.y, tx = threadIdx.x;
    __shared__ float Ws[16][17], Ps[16][17];
    float acc = 0.f;
    for (int p0 = 0; p0 < PP; p0 += 16) {
        Ws[ty][tx] = W1[(o0 + ty) * PP + p0 + tx];
        Ps[ty][tx] = pooled[((size_t)b * CH + (c0 + ty)) * PP + p0 + tx];
        __syncthreads();
#pragma unroll
        for (int p = 0; p < 16; ++p) acc += Ws[ty][p] * Ps[tx][p];
        __syncthreads();
    }
    Mmat[((size_t)b * FCH + o0 + ty) * CH + c0 + tx] = acc;
}

// ---------------------------------------------------------------------------
// Kernel 3: y1[b,o,hw] = (sum_c M[b,o,c]*feat[b,c,hw]) * rnorm[b,hw]  (f32)
__global__ void gemmY_k(const float* __restrict__ Mmat, const float* __restrict__ feat,
                        const float* __restrict__ rnorm, float* __restrict__ y1, int b0)
{
    int bl = blockIdx.z;
    int bg = b0 + bl;
    int brow = blockIdx.y * 64;
    int bcol = blockIdx.x * 64;
    const float* A  = Mmat + (size_t)bg * FCH * CH;
    const float* Bm = feat + (size_t)bg * CH * HWSZ;
    __shared__ float As[64][17];
    __shared__ float Bs[16][64];
    int tid = threadIdx.x;
    int tr = tid >> 4, tc = tid & 15;
    float acc[4][4] = {};
    for (int k0 = 0; k0 < CH; k0 += 16) {
        {
            int e = tid * 4;
            int r = e >> 4, col = e & 15;
            float4 v = *(const float4*)&A[(size_t)(brow + r) * CH + k0 + col];
            As[r][col] = v.x; As[r][col + 1] = v.y; As[r][col + 2] = v.z; As[r][col + 3] = v.w;
        }
        {
            int e = tid * 4;
            int r = e >> 6, col = e & 63;
            float4 v = *(const float4*)&Bm[(size_t)(k0 + r) * HWSZ + bcol + col];
            *(float4*)&Bs[r][col] = v;
        }
        __syncthreads();
#pragma unroll
        for (int k = 0; k < 16; ++k) {
            float a[4], bb[4];
#pragma unroll
            for (int i = 0; i < 4; ++i) a[i] = As[tr * 4 + i][k];
#pragma unroll
            for (int j = 0; j < 4; ++j) bb[j] = Bs[k][tc * 4 + j];
#pragma unroll
            for (int i = 0; i < 4; ++i)
#pragma unroll
                for (int j = 0; j < 4; ++j) acc[i][j] += a[i] * bb[j];
        }
        __syncthreads();
    }
    float4 rn = *(const float4*)&rnorm[(size_t)bg * HWSZ + bcol + tc * 4];
#pragma unroll
    for (int i = 0; i < 4; ++i) {
        float4 v;
        v.x = acc[i][0] * rn.x; v.y = acc[i][1] * rn.y;
        v.z = acc[i][2] * rn.z; v.w = acc[i][3] * rn.w;
        *(float4*)&y1[((size_t)bl * FCH + brow + tr * 4 + i) * HWSZ + bcol + tc * 4] = v;
    }
}

// ---------------------------------------------------------------------------
// Kernel 4: instance-norm stats per (b,o)
__global__ void instats_k(const float* __restrict__ y1, float* __restrict__ mu,
                          float* __restrict__ istd)
{
    int bo = blockIdx.x;
    const float* src = y1 + (size_t)bo * HWSZ;
    float s = 0.f, s2 = 0.f;
    for (int i = threadIdx.x; i < HWSZ; i += 256) {
        float v = src[i];
        s += v; s2 += v * v;
    }
#pragma unroll
    for (int off = 32; off > 0; off >>= 1) {
        s  += __shfl_down(s,  off, 64);
        s2 += __shfl_down(s2, off, 64);
    }
    __shared__ float sh[8];
    int wid = threadIdx.x >> 6, lane = threadIdx.x & 63;
    if (lane == 0) { sh[wid] = s; sh[4 + wid] = s2; }
    __syncthreads();
    if (threadIdx.x == 0) {
        float S  = sh[0] + sh[1] + sh[2] + sh[3];
        float S2 = sh[4] + sh[5] + sh[6] + sh[7];
        float m   = S  * (1.0f / HWSZ);
        float var = S2 * (1.0f / HWSZ) - m * m;
        if (var < 0.f) var = 0.f;
        mu[bo]   = m;
        istd[bo] = rsqrtf(var + 1e-5f);
    }
}

// ---------------------------------------------------------------------------
// Kernel 5 (fused): a = relu((y1-mu)*istd) -> bf16, transposed+padded layout
// apad[bl][row=h+1][cb=c/8][w+1][c%8], rows/cols 0 and 97 stay zero.
// grid: (96*3, 4, nb), 256 threads. Tile: 64 c x 32 w of one row.
__global__ void nt_k(const float* __restrict__ y1, const float* __restrict__ mu,
                     const float* __restrict__ istd, unsigned short* __restrict__ apad)
{
    int h = blockIdx.x / 3, wb = blockIdx.x % 3, w0 = wb * 32;
    int c0 = blockIdx.y * 64, bl = blockIdx.z;
    __shared__ float T[64][33];
    const float* yb = y1 + (size_t)bl * FCH * HWSZ;
    for (int e = threadIdx.x; e < 2048; e += 256) {
        int j = e & 31, c = e >> 5;
        int bo = bl * FCH + c0 + c;
        float v = (yb[(size_t)(c0 + c) * HWSZ + h * WW + w0 + j] - mu[bo]) * istd[bo];
        T[c][j] = v > 0.f ? v : 0.f;
    }
    __syncthreads();
    int cb = threadIdx.x >> 5, j = threadIdx.x & 31;
    union { unsigned short u[8]; uint4 v; } pk;
#pragma unroll
    for (int i = 0; i < 8; ++i) {
        __hip_bfloat16 hb = __float2bfloat16(T[cb * 8 + i][j]);
        pk.u[i] = *reinterpret_cast<unsigned short*>(&hb);
    }
    size_t chunk = ((size_t)(h + 1) * 32 + (c0 >> 3) + cb) * 98 + (w0 + j + 1);
    *(uint4*)(apad + (size_t)bl * APAD_ELEMS + chunk * 8) = pk.v;
}

// ---------------------------------------------------------------------------
// W2 repack: W2r2[s][cb][o][ci] = bf16(W2[o][cb*8+ci][s])
__global__ void repack_w2_k(const float* __restrict__ W2, unsigned short* __restrict__ W2r2)
{
    int e = blockIdx.x * 256 + threadIdx.x;     // 589824 total, exact
    int ci = e & 7, o = (e >> 3) & 255, cb = (e >> 11) & 31, s = e >> 16;
    int c = cb * 8 + ci;
    float v = W2[((size_t)o * 256 + c) * 9 + s];
    __hip_bfloat16 hb = __float2bfloat16(v);
    W2r2[e] = *reinterpret_cast<unsigned short*>(&hb);
}

// ---------------------------------------------------------------------------
__global__ void zero_k(uint4* __restrict__ p, size_t n)
{
    size_t i = (size_t)blockIdx.x * 256 + threadIdx.x;
    size_t stride = (size_t)gridDim.x * 256;
    uint4 z; z.x = 0; z.y = 0; z.z = 0; z.w = 0;
    for (; i < n; i += stride) p[i] = z;
}

// ---------------------------------------------------------------------------
// Kernel 6: 3x3 conv via implicit-GEMM MFMA (bf16 in, f32 acc)
// Block: 64 o x 2 rows x 96 w. 4 waves = 2(M) x 2(rows). K = 9 shifts x 256 c.
// grid: (48, 4, nb)
__global__ __launch_bounds__(256) void conv3m_k(const unsigned short* __restrict__ apad,
                                                const unsigned short* __restrict__ W2r2,
                                                const float* __restrict__ b2,
                                                float* __restrict__ out)
{
    int h0 = blockIdx.x * 2;
    int o0 = blockIdx.y * 64;
    int bl = blockIdx.z;
    int tid = threadIdx.x;
    int wave = tid >> 6, lane = tid & 63;
    int wm = wave >> 1, wn = wave & 1;
    int lr = lane & 15, kb = lane >> 4;

    __shared__ __align__(16) unsigned short As[9 * 4 * 64 * 8];   // 36864 B
    __shared__ __align__(16) unsigned short Bs[4 * 4 * 98 * 8];   // 25088 B

    const uint4* apadC = (const uint4*)(apad + (size_t)bl * APAD_ELEMS);
    const uint4* w2C   = (const uint4*)W2r2;
    uint4* AsC = (uint4*)As;
    uint4* BsC = (uint4*)Bs;
    const bf16x8* AsV = (const bf16x8*)As;
    const bf16x8* BsV = (const bf16x8*)Bs;

    f32x4 acc[2][6] = {};

    for (int c0 = 0; c0 < 256; c0 += 32) {
        int cb0 = c0 >> 3;
        // stage A: W2r2[s][cb0..cb0+4][o0..o0+64]  (2304 16B chunks)
        for (int e = tid; e < 2304; e += 256) {
            int o = e & 63, kk = (e >> 6) & 3, s = e >> 8;
            AsC[(s * 4 + kk) * 64 + o] = w2C[(size_t)(s * 32 + cb0 + kk) * 256 + o0 + o];
        }
        // stage B: apad rows h0..h0+3, cb0..cb0+4, all 98 w  (1568 16B chunks)
        for (int e = tid; e < 1568; e += 256) {
            int w = e % 98, r = e / 98;
            int kk = r & 3, rr = r >> 2;
            BsC[(rr * 4 + kk) * 98 + w] = apadC[(size_t)((h0 + rr) * 32 + cb0 + kk) * 98 + w];
        }
        __syncthreads();
#pragma unroll
        for (int kh = 0; kh < 3; ++kh) {
#pragma unroll
            for (int kw = 0; kw < 3; ++kw) {
                int s = kh * 3 + kw;
                bf16x8 af0 = AsV[(s * 4 + kb) * 64 + wm * 32 + lr];
                bf16x8 af1 = AsV[(s * 4 + kb) * 64 + wm * 32 + 16 + lr];
#pragma unroll
                for (int nf = 0; nf < 6; ++nf) {
                    bf16x8 bfr = BsV[((wn + kh) * 4 + kb) * 98 + nf * 16 + lr + kw];
                    acc[0][nf] = __builtin_amdgcn_mfma_f32_16x16x32_bf16(af0, bfr, acc[0][nf], 0, 0, 0);
                    acc[1][nf] = __builtin_amdgcn_mfma_f32_16x16x32_bf16(af1, bfr, acc[1][nf], 0, 0, 0);
                }
            }
        }
        __syncthreads();
    }

    // epilogue: C row=(lane>>4)*4+r (o), col=lane&15 (w)
    int h = h0 + wn;
    float* ob = out + (size_t)bl * FCH * HWSZ + (size_t)h * WW;
#pragma unroll
    for (int mf = 0; mf < 2; ++mf) {
#pragma unroll
        for (int r = 0; r < 4; ++r) {
            int o = o0 + wm * 32 + mf * 16 + kb * 4 + r;
            float bias = b2[o];
            float* orow = ob + (size_t)o * HWSZ;
#pragma unroll
            for (int nf = 0; nf < 6; ++nf)
                orow[nf * 16 + lr] = acc[mf][nf][r] + bias;
        }
    }
}

// ---------------------------------------------------------------------------
extern "C" void kernel_launch(void* const* d_in, const int* in_sizes, int n_in,
                              void* d_out, int out_size, void* d_ws, size_t ws_size,
                              hipStream_t stream)
{
    const float* Fir  = (const float*)d_in[0];
    const float* Fvis = (const float*)d_in[1];
    const float* W1   = (const float*)d_in[2];
    // d_in[3] = b1: canceled exactly by InstanceNorm -> unused
    const float* W2   = (const float*)d_in[4];
    const float* b2   = (const float*)d_in[5];
    float* out = (float*)d_out;

    char* w = (char*)d_ws;
    const size_t poolB = (size_t)BATCH * CH * PP * 4;      // 4 MB
    const size_t MB_   = (size_t)BATCH * FCH * CH * 4;     // 4 MB
    const size_t rnB   = (size_t)BATCH * HWSZ * 4;         // 0.56 MB
    const size_t stB   = (size_t)BATCH * FCH * 4;          // 16 KB
    const size_t w2rB  = (size_t)9 * 32 * 256 * 8 * 2;     // 1.125 MB
    const size_t fixed = poolB + MB_ + rnB + 2 * stB + w2rB;

    float* pooled = (float*)w;
    float* Mmat   = (float*)(w + poolB);
    float* rnorm  = (float*)(w + poolB + MB_);
    float* mu     = (float*)(w + poolB + MB_ + rnB);
    float* istd   = (float*)(w + poolB + MB_ + rnB + stB);
    unsigned short* W2r2 = (unsigned short*)(w + poolB + MB_ + rnB + 2 * stB);

    const size_t y1B   = (size_t)FCH * HWSZ * 4;           // 9.4 MB / batch
    const size_t apadB = (size_t)APAD_ELEMS * 2;           // 4.92 MB / batch
    const size_t perBatch = y1B + apadB;
    size_t avail = ws_size > fixed ? ws_size - fixed : 0;
    int NB = (int)(avail / perBatch);
    if (NB > BATCH) NB = BATCH;
    if (NB < 1) NB = 1;

    float* y1 = (float*)(w + fixed);
    unsigned short* apad = (unsigned short*)(w + fixed + (size_t)NB * y1B);

    repack_w2_k<<<2304, 256, 0, stream>>>(W2, W2r2);
    zero_k<<<2048, 256, 0, stream>>>((uint4*)apad, (size_t)NB * APAD_CHUNKS);

    for (int f = 0; f < 2; ++f) {
        const float* feat = (f == 0) ? Fir : Fvis;   // IR first in output
        float* o_ = out + (size_t)f * BATCH * FCH * HWSZ;

        pool16_k<<<BATCH * CH, 256, 0, stream>>>(feat, pooled);
        l2norm_k<<<dim3(HWSZ / 256, BATCH), 256, 0, stream>>>(feat, rnorm);
        gemmM_k<<<dim3(16, 16, BATCH), dim3(16, 16), 0, stream>>>(W1, pooled, Mmat);

        for (int b0 = 0; b0 < BATCH; b0 += NB) {
            int nb = BATCH - b0 < NB ? BATCH - b0 : NB;
            gemmY_k<<<dim3(HWSZ / 64, FCH / 64, nb), 256, 0, stream>>>(Mmat, feat, rnorm, y1, b0);
            instats_k<<<nb * FCH, 256, 0, stream>>>(y1, mu + (size_t)b0 * FCH, istd + (size_t)b0 * FCH);
            nt_k<<<dim3(96 * 3, 4, nb), 256, 0, stream>>>(y1, mu + (size_t)b0 * FCH,
                                                          istd + (size_t)b0 * FCH, apad);
            conv3m_k<<<dim3(48, 4, nb), 256, 0, stream>>>(apad, W2r2, b2,
                                                          o_ + (size_t)b0 * FCH * HWSZ);
        }
    }
}

// Round 3
// 719.685 us; speedup vs baseline: 59.3814x; 2.1816x over previous
//
#include <hip/hip_runtime.h>
#include <hip/hip_bf16.h>

#define BATCH 16
#define CH    256
#define HH    96
#define WW    96
#define HWSZ  9216     // 96*96
#define FCH   256
#define PP    256      // 16*16 pooled positions

typedef float f32x4 __attribute__((ext_vector_type(4)));
typedef short bf16x8 __attribute__((ext_vector_type(8)));
typedef unsigned short ushortT;

#define APAD_ELEMS 2458624   // 98*32*98*8 ushorts per batch
#define APAD_CHUNKS 307328   // uint4 chunks per batch

__device__ __forceinline__ void gload16(const void* g, void* l) {
    __builtin_amdgcn_global_load_lds((const __attribute__((address_space(1))) void*)g,
                                     (__attribute__((address_space(3))) void*)l, 16, 0, 0);
}
__device__ __forceinline__ float bfu2f(ushortT u) {
    return __uint_as_float(((unsigned)u) << 16);
}
__device__ __forceinline__ ushortT f2bfu(float f) {
    __hip_bfloat16 hb = __float2bfloat16(f);
    return *reinterpret_cast<ushortT*>(&hb);
}

// ---------------------------------------------------------------------------
// 6x6 average pool -> pooled[b,c,p] (f32, exact)
__global__ void pool16_k(const float* __restrict__ feat, float* __restrict__ pooled)
{
    int bc = blockIdx.x;
    const float* src = feat + (size_t)bc * HWSZ;
    int t = threadIdx.x;
    int pr = t >> 4, pc = t & 15;
    float s = 0.f;
#pragma unroll
    for (int i = 0; i < 6; ++i)
#pragma unroll
        for (int j = 0; j < 6; ++j)
            s += src[(pr * 6 + i) * WW + pc * 6 + j];
    pooled[(size_t)bc * PP + t] = s * (1.0f / 36.0f);
}

// ---------------------------------------------------------------------------
// fused: pack feat -> bf16 chunked [b][cb=32][hw][8ci]  +  rnorm[b,hw]
__global__ void fpack_k(const float* __restrict__ feat, ushortT* __restrict__ fpack,
                        float* __restrict__ rnorm)
{
    int b = blockIdx.y;
    int hw = blockIdx.x * 256 + threadIdx.x;
    const float* src = feat + (size_t)b * CH * HWSZ + hw;
    uint4* dst = (uint4*)fpack + (size_t)b * 32 * HWSZ + hw;
    float ss = 0.f;
    for (int cb = 0; cb < 32; ++cb) {
        union { ushortT u[8]; uint4 v; } pk;
#pragma unroll
        for (int i = 0; i < 8; ++i) {
            float v = src[(size_t)(cb * 8 + i) * HWSZ];
            ss += v * v;
            pk.u[i] = f2bfu(v);
        }
        dst[(size_t)cb * HWSZ] = pk.v;
    }
    rnorm[b * HWSZ + hw] = 1.0f / fmaxf(sqrtf(ss), 1e-12f);
}

// ---------------------------------------------------------------------------
// M[b,o,c] = sum_p W1[o,p] * pooled[b,c,p]  (f32 acc) -> bf16 packed
// Mb16[b][cb][o][ci]
__global__ void gemmM_k(const float* __restrict__ W1, const float* __restrict__ pooled,
                        ushortT* __restrict__ Mb16)
{
    int b = blockIdx.z;
    int o0 = blockIdx.y * 16, c0 = blockIdx.x * 16;
    int ty = threadIdx.y, tx = threadIdx.x;
    __shared__ float Ws[16][17], Ps[16][17];
    float acc = 0.f;
    for (int p0 = 0; p0 < PP; p0 += 16) {
        Ws[ty][tx] = W1[(o0 + ty) * PP + p0 + tx];
        Ps[ty][tx] = pooled[((size_t)b * CH + (c0 + ty)) * PP + p0 + tx];
        __syncthreads();
#pragma unroll
        for (int p = 0; p < 16; ++p) acc += Ws[ty][p] * Ps[tx][p];
        __syncthreads();
    }
    int c = c0 + tx, o = o0 + ty;
    Mb16[(((size_t)b * 32 + (c >> 3)) * 256 + o) * 8 + (c & 7)] = f2bfu(acc);
}

// ---------------------------------------------------------------------------
// W2 repack: W2r2[s][cb][o][ci] = bf16(W2[o][cb*8+ci][s])
__global__ void repack_w2_k(const float* __restrict__ W2, ushortT* __restrict__ W2r2)
{
    int e = blockIdx.x * 256 + threadIdx.x;     // 589824 total, exact
    int ci = e & 7, o = (e >> 3) & 255, cb = (e >> 11) & 31, s = e >> 16;
    int c = cb * 8 + ci;
    W2r2[e] = f2bfu(W2[((size_t)o * 256 + c) * 9 + s]);
}

// ---------------------------------------------------------------------------
__global__ void zero_k(uint4* __restrict__ p, size_t n)
{
    size_t i = (size_t)blockIdx.x * 256 + threadIdx.x;
    size_t stride = (size_t)gridDim.x * 256;
    uint4 z; z.x = 0; z.y = 0; z.z = 0; z.w = 0;
    for (; i < n; i += stride) p[i] = z;
}

// ---------------------------------------------------------------------------
// y1 GEMM via MFMA: y1[o,hw] = (sum_c M[o,c]*feat[c,hw]) * rnorm[hw]
// -> written bf16 (pre-norm) directly into apad padded layout.
// Block 128o x 128hw, 4 waves (2x2). grid (72, 2, nb)
__global__ __launch_bounds__(256, 4) void gemmYm_k(const ushortT* __restrict__ Mb16,
                                                   const ushortT* __restrict__ fpack,
                                                   const float* __restrict__ rnorm,
                                                   ushortT* __restrict__ apad, int b0)
{
    int bl = blockIdx.z, bg = b0 + bl;
    int hw0 = blockIdx.x * 128;
    int o0 = blockIdx.y * 128;
    int tid = threadIdx.x, wave = tid >> 6, lane = tid & 63;
    int wm = wave >> 1, wn = wave & 1;
    int lr = lane & 15, kb = lane >> 4;

    __shared__ __align__(16) char smem[34816];
    uint4* AsC = (uint4*)smem;                 // 512 chunks
    uint4* BsC = AsC + 512;                    // 512 chunks
    const bf16x8* AsV = (const bf16x8*)smem;
    const bf16x8* BsV = AsV + 512;
    ushortT* T = (ushortT*)smem;               // [128 hw][136 o-stride]

    const uint4* MbC = (const uint4*)Mb16 + (size_t)bg * 32 * 256;
    const uint4* fpC = (const uint4*)fpack + (size_t)bg * 32 * HWSZ;

    f32x4 acc[4][4] = {};

    for (int cb0 = 0; cb0 < 32; cb0 += 4) {
#pragma unroll
        for (int i = 0; i < 2; ++i) {
            int e = tid + i * 256;
            int kk = e >> 7, j = e & 127;
            gload16(MbC + (size_t)(cb0 + kk) * 256 + o0 + j, AsC + e);
            gload16(fpC + (size_t)(cb0 + kk) * HWSZ + hw0 + j, BsC + e);
        }
        __syncthreads();
        bf16x8 af[4], bfv[4];
#pragma unroll
        for (int mf = 0; mf < 4; ++mf) af[mf] = AsV[kb * 128 + wm * 64 + mf * 16 + lr];
#pragma unroll
        for (int nf = 0; nf < 4; ++nf) bfv[nf] = BsV[kb * 128 + wn * 64 + nf * 16 + lr];
#pragma unroll
        for (int mf = 0; mf < 4; ++mf)
#pragma unroll
            for (int nf = 0; nf < 4; ++nf)
                acc[mf][nf] = __builtin_amdgcn_mfma_f32_16x16x32_bf16(af[mf], bfv[nf], acc[mf][nf], 0, 0, 0);
        __syncthreads();
    }

    float rn[4];
#pragma unroll
    for (int nf = 0; nf < 4; ++nf)
        rn[nf] = rnorm[(size_t)bg * HWSZ + hw0 + wn * 64 + nf * 16 + lr];

    // transpose through LDS: T[hw_local][o_local]
#pragma unroll
    for (int mf = 0; mf < 4; ++mf)
#pragma unroll
        for (int nf = 0; nf < 4; ++nf)
#pragma unroll
            for (int r = 0; r < 4; ++r)
                T[(wn * 64 + nf * 16 + lr) * 136 + wm * 64 + mf * 16 + kb * 4 + r] =
                    f2bfu(acc[mf][nf][r] * rn[nf]);
    __syncthreads();

    uint4* apC = (uint4*)apad + (size_t)bl * APAD_CHUNKS;
    int ob0 = blockIdx.y * 16;
#pragma unroll
    for (int i = 0; i < 8; ++i) {
        int e = tid + i * 256;
        int hw_l = e >> 4, ob = e & 15;
        uint4 v = *(uint4*)&T[hw_l * 136 + ob * 8];
        int hw = hw0 + hw_l;
        int h = hw / 96, w = hw - h * 96;
        apC[(size_t)((h + 1) * 32 + ob0 + ob) * 98 + (w + 1)] = v;
    }
}

// ---------------------------------------------------------------------------
// instance-norm stats from apad (bf16): per (bl, ob) block -> 8 o's
// grid (32, nb)
__global__ void instats2_k(const ushortT* __restrict__ apad, float* __restrict__ mu,
                           float* __restrict__ istd)
{
    int ob = blockIdx.x, bl = blockIdx.y;
    const uint4* apC = (const uint4*)apad + (size_t)bl * APAD_CHUNKS;
    float s[8] = {}, s2[8] = {};
    for (int e = threadIdx.x; e < HWSZ; e += 256) {
        int row = e / 96;
        int w = e - row * 96;
        uint4 v = apC[(size_t)((row + 1) * 32 + ob) * 98 + w + 1];
        const ushortT* u = (const ushortT*)&v;
#pragma unroll
        for (int k = 0; k < 8; ++k) {
            float f = bfu2f(u[k]);
            s[k] += f; s2[k] += f * f;
        }
    }
#pragma unroll
    for (int off = 32; off > 0; off >>= 1) {
#pragma unroll
        for (int k = 0; k < 8; ++k) {
            s[k]  += __shfl_down(s[k],  off, 64);
            s2[k] += __shfl_down(s2[k], off, 64);
        }
    }
    __shared__ float sh[4][16];
    int wid = threadIdx.x >> 6;
    if ((threadIdx.x & 63) == 0) {
#pragma unroll
        for (int k = 0; k < 8; ++k) { sh[wid][k] = s[k]; sh[wid][8 + k] = s2[k]; }
    }
    __syncthreads();
    if (threadIdx.x < 8) {
        int k = threadIdx.x;
        float S  = sh[0][k] + sh[1][k] + sh[2][k] + sh[3][k];
        float S2 = sh[0][8 + k] + sh[1][8 + k] + sh[2][8 + k] + sh[3][8 + k];
        float m   = S * (1.0f / HWSZ);
        float var = S2 * (1.0f / HWSZ) - m * m;
        if (var < 0.f) var = 0.f;
        mu[bl * 256 + ob * 8 + k]   = m;
        istd[bl * 256 + ob * 8 + k] = rsqrtf(var + 1e-5f);
    }
}

// ---------------------------------------------------------------------------
// in-place normalize+relu on apad interior. grid (96, nb)
__global__ void nr_k(ushortT* __restrict__ apad, const float* __restrict__ mu,
                     const float* __restrict__ istd)
{
    int row = blockIdx.x + 1, bl = blockIdx.y;
    __shared__ float smu[256], sis[256];
    smu[threadIdx.x] = mu[bl * 256 + threadIdx.x];
    sis[threadIdx.x] = istd[bl * 256 + threadIdx.x];
    __syncthreads();
    uint4* apC = (uint4*)apad + (size_t)bl * APAD_CHUNKS + (size_t)row * 32 * 98;
    for (int e = threadIdx.x; e < 3072; e += 256) {
        int ob = e / 96;
        int w = e - ob * 96 + 1;
        uint4 v = apC[(size_t)ob * 98 + w];
        ushortT* u = (ushortT*)&v;
#pragma unroll
        for (int k = 0; k < 8; ++k) {
            float f = (bfu2f(u[k]) - smu[ob * 8 + k]) * sis[ob * 8 + k];
            u[k] = f2bfu(f > 0.f ? f : 0.f);
        }
        apC[(size_t)ob * 98 + w] = v;
    }
}

// ---------------------------------------------------------------------------
// 3x3 conv implicit-GEMM MFMA v2.
// Block: 64 o x 2 rows x 96 w; 4 waves = 2 rows x 2 w-halves; acc[4][3].
// K-loop: kh(3) x c-chunk(8); A,B staged via global_load_lds. LDS 28.7KB.
// grid (48, 4, nb)
__global__ __launch_bounds__(256, 4) void conv3m2_k(const ushortT* __restrict__ apad,
                                                    const ushortT* __restrict__ W2r2,
                                                    const float* __restrict__ b2,
                                                    float* __restrict__ out)
{
    int h0 = blockIdx.x * 2;
    int o0 = blockIdx.y * 64;
    int bl = blockIdx.z;
    int tid = threadIdx.x;
    int wave = tid >> 6, lane = tid & 63;
    int wr = wave >> 1, wh = wave & 1;
    int lr = lane & 15, kb = lane >> 4;

    __shared__ __align__(16) ushortT As[768 * 8];    // [kw3][kk4][o64] chunks
    __shared__ __align__(16) ushortT Bs[1024 * 8];   // [rr2*4+kk][w98] chunks (784 used)

    const uint4* apadC = (const uint4*)apad + (size_t)bl * APAD_CHUNKS;
    const uint4* w2C   = (const uint4*)W2r2;
    uint4* AsC = (uint4*)As;
    uint4* BsC = (uint4*)Bs;
    const bf16x8* AsV = (const bf16x8*)As;
    const bf16x8* BsV = (const bf16x8*)Bs;

    f32x4 acc[4][3] = {};

    for (int kh = 0; kh < 3; ++kh) {
        for (int c0 = 0; c0 < 256; c0 += 32) {
            int cb0 = c0 >> 3;
#pragma unroll
            for (int i = 0; i < 3; ++i) {       // A: 768 chunks exact
                int e = tid + i * 256;
                int o = e & 63, kk = (e >> 6) & 3, kw = e >> 8;
                gload16(w2C + (size_t)((kh * 3 + kw) * 32 + cb0 + kk) * 256 + o0 + o, AsC + e);
            }
#pragma unroll
            for (int i = 0; i < 4; ++i) {       // B: 784 chunks, padded to 1024
                int e = tid + i * 256;
                int se = e < 784 ? e : 783;
                int w = se % 98, r = se / 98;
                int rr = r >> 2, kk = r & 3;
                gload16(apadC + (size_t)((h0 + kh + rr) * 32 + cb0 + kk) * 98 + w, BsC + e);
            }
            __syncthreads();
#pragma unroll
            for (int kw = 0; kw < 3; ++kw) {
                bf16x8 af[4];
#pragma unroll
                for (int mf = 0; mf < 4; ++mf)
                    af[mf] = AsV[(kw * 4 + kb) * 64 + mf * 16 + lr];
#pragma unroll
                for (int nf = 0; nf < 3; ++nf) {
                    bf16x8 bfr = BsV[(wr * 4 + kb) * 98 + wh * 48 + nf * 16 + lr + kw];
#pragma unroll
                    for (int mf = 0; mf < 4; ++mf)
                        acc[mf][nf] = __builtin_amdgcn_mfma_f32_16x16x32_bf16(af[mf], bfr, acc[mf][nf], 0, 0, 0);
                }
            }
            __syncthreads();
        }
    }

    int h = h0 + wr;
    float* obase = out + (size_t)bl * FCH * HWSZ + (size_t)h * WW + wh * 48;
#pragma unroll
    for (int mf = 0; mf < 4; ++mf) {
#pragma unroll
        for (int r = 0; r < 4; ++r) {
            int o = o0 + mf * 16 + kb * 4 + r;
            float bias = b2[o];
            float* orow = obase + (size_t)o * HWSZ;
#pragma unroll
            for (int nf = 0; nf < 3; ++nf)
                orow[nf * 16 + lr] = acc[mf][nf][r] + bias;
        }
    }
}

// ---------------------------------------------------------------------------
extern "C" void kernel_launch(void* const* d_in, const int* in_sizes, int n_in,
                              void* d_out, int out_size, void* d_ws, size_t ws_size,
                              hipStream_t stream)
{
    const float* Fir  = (const float*)d_in[0];
    const float* Fvis = (const float*)d_in[1];
    const float* W1   = (const float*)d_in[2];
    // d_in[3] = b1: canceled exactly by InstanceNorm -> unused
    const float* W2   = (const float*)d_in[4];
    const float* b2   = (const float*)d_in[5];
    float* out = (float*)d_out;

    char* w = (char*)d_ws;
    const size_t poolB = (size_t)BATCH * CH * PP * 4;        // 4 MB
    const size_t MbB   = (size_t)BATCH * 32 * 256 * 8 * 2;   // 2 MB
    const size_t rnB   = (size_t)BATCH * HWSZ * 4;           // 0.56 MB
    const size_t stB   = (size_t)BATCH * FCH * 4;            // 16 KB
    const size_t w2rB  = (size_t)9 * 32 * 256 * 8 * 2;       // 1.125 MB
    const size_t fpB   = (size_t)BATCH * 32 * HWSZ * 8 * 2;  // 75.5 MB

    size_t off = 0;
    float*   pooled = (float*)(w + off);   off += poolB;
    ushortT* Mb16   = (ushortT*)(w + off); off += MbB;
    float*   rnorm  = (float*)(w + off);   off += rnB;
    float*   mu     = (float*)(w + off);   off += stB;
    float*   istd   = (float*)(w + off);   off += stB;
    ushortT* W2r2   = (ushortT*)(w + off); off += w2rB;
    ushortT* fpack  = (ushortT*)(w + off); off += fpB;
    const size_t fixed = off;

    const size_t apadB = (size_t)APAD_ELEMS * 2;             // 4.92 MB / batch
    size_t avail = ws_size > fixed ? ws_size - fixed : 0;
    int NB = (int)(avail / apadB);
    if (NB > BATCH) NB = BATCH;
    if (NB < 1) NB = 1;
    ushortT* apad = (ushortT*)(w + fixed);

    repack_w2_k<<<2304, 256, 0, stream>>>(W2, W2r2);
    zero_k<<<2048, 256, 0, stream>>>((uint4*)apad, (size_t)NB * APAD_CHUNKS);

    for (int f = 0; f < 2; ++f) {
        const float* feat = (f == 0) ? Fir : Fvis;   // IR first in output
        float* o_ = out + (size_t)f * BATCH * FCH * HWSZ;

        fpack_k<<<dim3(36, BATCH), 256, 0, stream>>>(feat, fpack, rnorm);
        pool16_k<<<BATCH * CH, 256, 0, stream>>>(feat, pooled);
        gemmM_k<<<dim3(16, 16, BATCH), dim3(16, 16), 0, stream>>>(W1, pooled, Mb16);

        for (int b0 = 0; b0 < BATCH; b0 += NB) {
            int nb = BATCH - b0 < NB ? BATCH - b0 : NB;
            gemmYm_k<<<dim3(72, 2, nb), 256, 0, stream>>>(Mb16, fpack, rnorm, apad, b0);
            instats2_k<<<dim3(32, nb), 256, 0, stream>>>(apad, mu, istd);
            nr_k<<<dim3(96, nb), 256, 0, stream>>>(apad, mu, istd);
            conv3m2_k<<<dim3(48, 4, nb), 256, 0, stream>>>(apad, W2r2, b2,
                                                           o_ + (size_t)b0 * FCH * HWSZ);
        }
    }
}